// Round 21
// baseline (154.765 us; speedup 1.0000x reference)
//
#include <hip/hip_runtime.h>
#include <stdint.h>

#define TOK   8192
#define DIM   1024
#define NEXP  8
#define TOPK  2
#define WPAD  1028

typedef unsigned short ushort_t;
typedef __attribute__((ext_vector_type(8))) short bf16x8;
typedef __attribute__((ext_vector_type(4))) float f32x4;

__device__ __forceinline__ unsigned short f2bf(float f) {
  unsigned int u = __float_as_uint(f);
  u += 0x7fffu + ((u >> 16) & 1u);
  return (unsigned short)(u >> 16);
}
__device__ __forceinline__ float bf2f(ushort_t u) {
  return __uint_as_float(((unsigned int)u) << 16);
}

__device__ __forceinline__ void gload_lds16(const void* g, void* l) {
  __builtin_amdgcn_global_load_lds(
      (const __attribute__((address_space(1))) void*)(uintptr_t)g,
      (__attribute__((address_space(3))) void*)(unsigned int)(uintptr_t)l,
      16, 0, 0);
}

// ---- prep: router+cast+histogram (0..511) | Wsh1/Wgu transpose (512..1791) --
__global__ __launch_bounds__(256) void k_prep(
    const float* __restrict__ x, const float* __restrict__ Wg,
    ushort_t* __restrict__ xb, int* __restrict__ tid, float* __restrict__ tw,
    int* __restrict__ cnt,
    const float* __restrict__ sg, const float* __restrict__ su,
    const float* __restrict__ wgm, const float* __restrict__ wu,
    ushort_t* __restrict__ Wsh1, ushort_t* __restrict__ Wgu) {
  __shared__ float sm[WPAD * NEXP > 64 * 65 ? WPAD * NEXP : 64 * 65];
  __shared__ int hh[NEXP];
  if (blockIdx.x < 512) {
    if (threadIdx.x < NEXP) hh[threadIdx.x] = 0;
    for (int j = threadIdx.x; j < DIM * NEXP; j += 256)
      sm[(j & 7) * WPAD + (j >> 3)] = Wg[j];
    __syncthreads();
    const int wid = threadIdx.x >> 6, lane = threadIdx.x & 63;
#pragma unroll
    for (int tt2 = 0; tt2 < 4; ++tt2) {
      const int t = blockIdx.x * 16 + wid * 4 + tt2;
      const float* xr = x + (size_t)t * DIM;
      ushort_t* xw = xb + (size_t)t * DIM;
      float acc[NEXP];
#pragma unroll
      for (int e = 0; e < NEXP; ++e) acc[e] = 0.f;
#pragma unroll
      for (int k = 0; k < 4; ++k) {
        const int i = k * 256 + lane * 4;
        const float4 xv = *(const float4*)(xr + i);
        union { ushort_t u[4]; uint2 v; } s;
        s.u[0] = f2bf(xv.x); s.u[1] = f2bf(xv.y);
        s.u[2] = f2bf(xv.z); s.u[3] = f2bf(xv.w);
        *(uint2*)(xw + i) = s.v;
#pragma unroll
        for (int e = 0; e < NEXP; ++e) {
          const float4 wv = *(const float4*)&sm[e * WPAD + i];
          acc[e] += xv.x * wv.x + xv.y * wv.y + xv.z * wv.z + xv.w * wv.w;
        }
      }
#pragma unroll
      for (int e = 0; e < NEXP; ++e) {
        float v = acc[e];
#pragma unroll
        for (int o = 32; o > 0; o >>= 1) v += __shfl_xor(v, o);
        acc[e] = v;
      }
      if (lane == 0) {
        float mx = acc[0];
#pragma unroll
        for (int e = 1; e < NEXP; ++e) mx = fmaxf(mx, acc[e]);
        float p[NEXP]; float s = 0.f;
#pragma unroll
        for (int e = 0; e < NEXP; ++e) { p[e] = __expf(acc[e] - mx); s += p[e]; }
        const float inv = 1.f / s;
#pragma unroll
        for (int e = 0; e < NEXP; ++e) p[e] *= inv;
        int i1 = 0; float s1 = p[0];
#pragma unroll
        for (int e = 1; e < NEXP; ++e) if (p[e] > s1) { s1 = p[e]; i1 = e; }
        int i2 = -1; float s2 = -1.f;
#pragma unroll
        for (int e = 0; e < NEXP; ++e) if (e != i1 && p[e] > s2) { s2 = p[e]; i2 = e; }
        tid[t * 2] = i1; tid[t * 2 + 1] = i2;
        tw[t * 2] = s1;  tw[t * 2 + 1] = s2;
        atomicAdd(&hh[i1], 1);
        atomicAdd(&hh[i2], 1);
      }
    }
    __syncthreads();
    if (threadIdx.x < NEXP) {
      const int v = hh[threadIdx.x];
      if (v) atomicAdd(&cnt[threadIdx.x], v);
    }
    return;
  }
  // ---- transpose (ilv only): one 64x64 tile per block ----
  int b = blockIdx.x - 512;
  const float* src; ushort_t* dst; int R, C, r0, c0, pp;
  if (b < 256) {
    pp = b & 1; const int t = b >> 1;
    src = pp ? su : sg; dst = Wsh1; R = 1024; C = 512;
    c0 = (t & 7) * 64; r0 = (t >> 3) * 64;
  } else {
    b -= 256; pp = b & 1; const int t = b >> 1;
    const int e = t >> 6; const int tt = t & 63;
    src = (pp ? wu : wgm) + (size_t)e * 1024 * 256;
    dst = Wgu + (size_t)e * 512 * 1024; R = 1024; C = 256;
    c0 = (tt & 3) * 64; r0 = (tt >> 2) * 64;
  }
  float (*tt4)[65] = (float(*)[65])sm;
  const int row16 = threadIdx.x >> 4;
  const int q16   = threadIdx.x & 15;
#pragma unroll
  for (int i = 0; i < 64; i += 16) {
    const float4 v = *(const float4*)&src[(size_t)(r0 + row16 + i) * C + c0 + q16 * 4];
    tt4[q16 * 4 + 0][row16 + i] = v.x;
    tt4[q16 * 4 + 1][row16 + i] = v.y;
    tt4[q16 * 4 + 2][row16 + i] = v.z;
    tt4[q16 * 4 + 3][row16 + i] = v.w;
  }
  __syncthreads();
#pragma unroll
  for (int i = 0; i < 64; i += 16) {
    const int n = c0 + row16 + i;
    const int drow = 2 * n + pp;
    const float4 v = *(const float4*)&tt4[row16 + i][q16 * 4];
    union { ushort_t u[4]; uint2 w; } s4;
    s4.u[0] = f2bf(v.x); s4.u[1] = f2bf(v.y);
    s4.u[2] = f2bf(v.z); s4.u[3] = f2bf(v.w);
    *(uint2*)&dst[(size_t)drow * R + r0 + q16 * 4] = s4.w;
  }
}

// ---------------- ballot-ranked scatter (inline off from cnt) ----------------
__global__ __launch_bounds__(256) void k_scatter(const int* __restrict__ tid,
                                                 const float* __restrict__ tw,
                                                 const int* __restrict__ cnt,
                                                 int* __restrict__ cnt2,
                                                 int* __restrict__ tok,
                                                 float* __restrict__ wgt,
                                                 int* __restrict__ dstrow) {
  int offv[NEXP];
  {
    int run = 0;
#pragma unroll
    for (int e = 0; e < NEXP; ++e) { offv[e] = run; run += cnt[e]; }
  }
  const int t = blockIdx.x * 256 + threadIdx.x;
  const int lane = threadIdx.x & 63;
#pragma unroll
  for (int j = 0; j < TOPK; ++j) {
    const int e = tid[t * 2 + j];
    const float w = tw[t * 2 + j];
    int slot = 0;
#pragma unroll
    for (int ee = 0; ee < NEXP; ++ee) {
      const unsigned long long m = __ballot(e == ee);
      if (m) {
        const int r = __popcll(m & ((1ull << lane) - 1ull));
        const int leader = __ffsll((unsigned long long)m) - 1;
        int base = 0;
        if (lane == leader) base = atomicAdd(&cnt2[ee], (int)__popcll(m));
        base = __shfl(base, leader);
        if (e == ee) slot = offv[ee] + base + r;
      }
    }
    tok[slot] = t;
    wgt[slot] = w;
    dstrow[slot] = t * 2 + j;
  }
}

// ---- GEMM1 (merged routed+shared, r13 structure) + Wsd/Wd transpose tail ----
__global__ __launch_bounds__(256) void k_gemm1(
    const ushort_t* __restrict__ A0, const ushort_t* __restrict__ Bgu,
    const ushort_t* __restrict__ Bsh,
    ushort_t* __restrict__ he, ushort_t* __restrict__ hs,
    const int* __restrict__ tok, const int* __restrict__ cnt,
    const float* __restrict__ sd, const float* __restrict__ wdn,
    ushort_t* __restrict__ Wsd, ushort_t* __restrict__ Wd) {
  constexpr int K = 1024, NB = 4, NGROUP = 16, MBSLOT = 16;
  constexpr int NWG = NGROUP * MBSLOT * NB;
  __shared__ __attribute__((aligned(16))) ushort_t lA[2][128 * 64];
  __shared__ __attribute__((aligned(16))) ushort_t lB[2][128 * 64];

  if (blockIdx.x >= 1024) {
    int b = blockIdx.x - 1024;
    const float* src; ushort_t* dst; int R, C, r0, c0;
    if (b < 128) {
      src = sd; dst = Wsd; R = 512; C = 1024;
      c0 = (b & 15) * 64; r0 = (b >> 4) * 64;
    } else {
      b -= 128; const int e = b >> 6; const int tt = b & 63;
      src = wdn + (size_t)e * 256 * 1024;
      dst = Wd + (size_t)e * 1024 * 256; R = 256; C = 1024;
      c0 = (tt & 15) * 64; r0 = (tt >> 4) * 64;
    }
    float (*tt4)[65] = (float(*)[65])lA;
    const int row16 = threadIdx.x >> 4;
    const int q16   = threadIdx.x & 15;
#pragma unroll
    for (int i = 0; i < 64; i += 16) {
      const float4 v = *(const float4*)&src[(size_t)(r0 + row16 + i) * C + c0 + q16 * 4];
      tt4[q16 * 4 + 0][row16 + i] = v.x;
      tt4[q16 * 4 + 1][row16 + i] = v.y;
      tt4[q16 * 4 + 2][row16 + i] = v.z;
      tt4[q16 * 4 + 3][row16 + i] = v.w;
    }
    __syncthreads();
#pragma unroll
    for (int i = 0; i < 64; i += 16) {
      const int n = c0 + row16 + i;
      const float4 v = *(const float4*)&tt4[row16 + i][q16 * 4];
      union { ushort_t u[4]; uint2 w; } s4;
      s4.u[0] = f2bf(v.x); s4.u[1] = f2bf(v.y);
      s4.u[2] = f2bf(v.z); s4.u[3] = f2bf(v.w);
      *(uint2*)&dst[(size_t)n * R + r0 + q16 * 4] = s4.w;
    }
    return;
  }

  const int wg = (blockIdx.x % 8) * (NWG / 8) + blockIdx.x / 8;
  const int g = wg / (MBSLOT * NB);
  const int rem = wg % (MBSLOT * NB);
  const int mbslot = rem / NB;
  const int nb = rem % NB;
  const int nBase = nb * 128;

  int m_e, offE = 0, rowq = 0, hh = 0;
  bool gat = false;
  const ushort_t* Abase = A0;
  const ushort_t* Bblk;
  if (g < 8) {
    gat = true; m_e = cnt[g];
    for (int e = 0; e < NEXP; ++e) offE += (e < g) ? cnt[e] : 0;
    Bblk = Bgu + (size_t)g * 512 * 1024;
  } else {
    const int q = (g - 8) >> 1; hh = (g - 8) & 1;
    rowq = q * 2048; m_e = 2048;
    Abase = A0 + (size_t)rowq * 1024;
    Bblk = Bsh + (size_t)hh * 512 * 1024;
  }
  if (m_e == 0) return;

  const int wid = threadIdx.x >> 6, lane = threadIdx.x & 63;
  const int wm = wid >> 1, wn = wid & 1;
  const int l15 = lane & 15, lq = lane >> 4;

  const ushort_t* bptr[4];
#pragma unroll
  for (int cc = 0; cc < 4; ++cc) {
    const int c = wid * 4 + cc;
    const int rl = c * 8 + (lane >> 3);
    const int slot = (lane & 7) ^ (rl & 7);
    bptr[cc] = Bblk + (size_t)(nBase + rl) * K + slot * 8;
  }

  for (int mb = mbslot; mb * 128 < m_e; mb += MBSLOT) {
    const int mBase = mb * 128;
    const ushort_t* aptr[4];
#pragma unroll
    for (int cc = 0; cc < 4; ++cc) {
      const int c = wid * 4 + cc;
      const int rl = c * 8 + (lane >> 3);
      const int slot = (lane & 7) ^ (rl & 7);
      const int gr = mBase + rl;
      const int gc = (gr < m_e) ? gr : (m_e - 1);
      const ushort_t* ar;
      if (gat) ar = A0 + (size_t)tok[offE + gc] * 1024;
      else     ar = Abase + (size_t)gc * K;
      aptr[cc] = ar + slot * 8;
    }

    auto stage = [&](int buf, int ktv) {
#pragma unroll
      for (int cc = 0; cc < 4; ++cc) {
        const int c = wid * 4 + cc;
        gload_lds16(aptr[cc] + ktv, &lA[buf][c * 512]);
        gload_lds16(bptr[cc] + ktv, &lB[buf][c * 512]);
      }
    };

    f32x4 acc[4][4];
#pragma unroll
    for (int mi = 0; mi < 4; ++mi)
#pragma unroll
      for (int ni = 0; ni < 4; ++ni) acc[mi][ni] = (f32x4){0.f, 0.f, 0.f, 0.f};

    stage(0, 0);
    int cur = 0;
    for (int kt = 0; kt < K; kt += 64) {
      if (kt + 64 < K) {
        stage(cur ^ 1, kt + 64);
        asm volatile("s_waitcnt vmcnt(8)" ::: "memory");
      } else {
        asm volatile("s_waitcnt vmcnt(0)" ::: "memory");
      }
      __builtin_amdgcn_s_barrier();
#pragma unroll
      for (int kk = 0; kk < 2; ++kk) {
        bf16x8 af[4], bfr[4];
#pragma unroll
        for (int mi = 0; mi < 4; ++mi) {
          const int row = wm * 64 + mi * 16 + l15;
          const int cb = ((kk * 32 + lq * 8) * 2) ^ ((row & 7) << 4);
          af[mi] = *(const bf16x8*)((const char*)lA + cur * 16384 + row * 128 + cb);
        }
#pragma unroll
        for (int ni = 0; ni < 4; ++ni) {
          const int row = wn * 64 + ni * 16 + l15;
          const int cb = ((kk * 32 + lq * 8) * 2) ^ ((row & 7) << 4);
          bfr[ni] = *(const bf16x8*)((const char*)lB + cur * 16384 + row * 128 + cb);
        }
#pragma unroll
        for (int mi = 0; mi < 4; ++mi)
#pragma unroll
          for (int ni = 0; ni < 4; ++ni)
            acc[mi][ni] = __builtin_amdgcn_mfma_f32_16x16x32_bf16(
                af[mi], bfr[ni], acc[mi][ni], 0, 0, 0);
      }
      __builtin_amdgcn_s_barrier();
      cur ^= 1;
    }

#pragma unroll
    for (int mi = 0; mi < 4; ++mi) {
#pragma unroll
      for (int r = 0; r < 4; ++r) {
        const int gg = mBase + wm * 64 + mi * 16 + lq * 4 + r;
        const bool ok = gg < m_e;
#pragma unroll
        for (int ni = 0; ni < 4; ++ni) {
          const float v = acc[mi][ni][r];
          const int c = nBase + wn * 64 + ni * 16 + l15;
          const float o = __shfl_xor(v, 1);
          if (!(c & 1) && ok) {
            const float hv = (v / (1.f + __expf(-v))) * o;
            if (gat) he[(size_t)(offE + gg) * 256 + (c >> 1)] = f2bf(hv);
            else     hs[(size_t)(rowq + gg) * 512 + hh * 256 + (c >> 1)] = f2bf(hv);
          }
        }
      }
    }
  }
}

// ---- GEMM2r: routed. 64-col B strips (32KB) -> 2 blocks/CU, barrier-free ----
// Grid 512 x 512thr. e = bid&7 (==XCD). c0=bid>>3: nb=c0&15 (16 strips of 64),
// mslot=c0>>4 (4). Wave tile 32m x 64n; per-wave lA dbuf 2x4KB.
__global__ __launch_bounds__(512, 4) void k_gemm2r(
    const ushort_t* __restrict__ he, const ushort_t* __restrict__ Wd,
    ushort_t* __restrict__ contrib, const float* __restrict__ wgt,
    const int* __restrict__ cnt, const int* __restrict__ dstrow) {
  constexpr int K = 256;
  __shared__ __attribute__((aligned(16))) ushort_t lB[64 * 256];      // 32KB
  __shared__ __attribute__((aligned(16))) ushort_t lA[8][2][32 * 64]; // 32KB

  const int e = blockIdx.x & 7;
  const int c0 = blockIdx.x >> 3;
  const int nb = c0 & 15;
  const int mslot = c0 >> 4;
  const int nBase = nb * 64;

  const int m_e = cnt[e];
  int offE = 0;
  for (int ee = 0; ee < NEXP; ++ee) offE += (ee < e) ? cnt[ee] : 0;
  const ushort_t* Abase = he + (size_t)offE * K;
  const ushort_t* Bblk = Wd + (size_t)e * 1024 * K;

  const int wid = threadIdx.x >> 6, lane = threadIdx.x & 63;
  const int l15 = lane & 15, lq = lane >> 4;

  if (m_e > 0) {
    // stage B: 2048 16B-slots, 512 thr x 4 (linear dest, swizzled source)
#pragma unroll
    for (int i = 0; i < 4; ++i) {
      const int L = i * 512 + threadIdx.x;
      const int row = L >> 5, s = L & 31;
      const int ss = s ^ (row & 31);
      gload_lds16(Bblk + (size_t)(nBase + row) * K + ss * 8,
                  ((char*)lB) + (size_t)(L & ~63) * 16);
    }
  }

  char* lAw = (char*)&lA[wid][0][0];
  auto stageA = [&](int buf, int chunk, int kc) {
#pragma unroll
    for (int i = 0; i < 4; ++i) {
      const int L = i * 64 + lane;
      const int row = L >> 3, s = L & 7;
      const int ss = s ^ (row & 7);
      int gr = chunk * 32 + row;
      if (gr >= m_e) gr = m_e - 1;
      gload_lds16(Abase + (size_t)gr * K + kc * 64 + ss * 8,
                  lAw + (size_t)buf * 4096 + (size_t)i * 1024);
    }
  };

  int cw = mslot * 8 + wid;
  bool active = (m_e > 0) && (cw * 32 < m_e);
  if (m_e > 0) stageA(0, active ? cw : 0, 0);
  // this wave's 4 B-loads are oldest; 4 A-loads newest -> vmcnt(4) retires B
  asm volatile("s_waitcnt vmcnt(4)" ::: "memory");
  __builtin_amdgcn_s_barrier();
  if (!active) return;

  int buf = 0;
  while (active) {
    f32x4 acc[2][4];
#pragma unroll
    for (int mi = 0; mi < 2; ++mi)
#pragma unroll
      for (int ni = 0; ni < 4; ++ni) acc[mi][ni] = (f32x4){0.f, 0.f, 0.f, 0.f};

    for (int kc = 0; kc < 4; ++kc) {
      int nc = cw, nk = kc + 1;
      if (nk == 4) { nk = 0; nc = cw + 32; }
      if (nc * 32 < m_e) {
        stageA(buf ^ 1, nc, nk);
        asm volatile("s_waitcnt vmcnt(4)" ::: "memory");
      } else {
        asm volatile("s_waitcnt vmcnt(0)" ::: "memory");
      }
      const char* sA = lAw + buf * 4096;
#pragma unroll
      for (int kk = 0; kk < 2; ++kk) {
        bf16x8 af[2], bfr[4];
#pragma unroll
        for (int mi = 0; mi < 2; ++mi) {
          const int row = mi * 16 + l15;
          af[mi] = *(const bf16x8*)(sA + row * 128 + (((kk * 4 + lq) ^ (row & 7)) << 4));
        }
#pragma unroll
        for (int ni = 0; ni < 4; ++ni) {
          const int brow = ni * 16 + l15;
          const int ck = kc * 8 + kk * 4 + lq;
          bfr[ni] = *(const bf16x8*)((const char*)lB + brow * 512 +
                                     ((ck ^ (brow & 31)) << 4));
        }
#pragma unroll
        for (int mi = 0; mi < 2; ++mi)
#pragma unroll
          for (int ni = 0; ni < 4; ++ni)
            acc[mi][ni] = __builtin_amdgcn_mfma_f32_16x16x32_bf16(
                af[mi], bfr[ni], acc[mi][ni], 0, 0, 0);
      }
      buf ^= 1;
    }

#pragma unroll
    for (int mi = 0; mi < 2; ++mi) {
#pragma unroll
      for (int r = 0; r < 4; ++r) {
        const int gg = cw * 32 + mi * 16 + lq * 4 + r;
        if (gg < m_e) {
          const float w = wgt[offE + gg];
          const int dr = dstrow[offE + gg];
#pragma unroll
          for (int ni = 0; ni < 4; ++ni) {
            const int c = nBase + ni * 16 + l15;
            contrib[(size_t)dr * 1024 + c] = f2bf(acc[mi][ni][r] * w);
          }
        }
      }
    }
    cw += 32;
    active = cw * 32 < m_e;
  }
  asm volatile("s_waitcnt vmcnt(0)" ::: "memory");
}

// ---- GEMM2s: shared+combine. 32-col B strips (32KB) -> 2 blocks/CU ---------
// Grid 512 x 512thr. xcd=bid&7 -> token range 1024. c0=bid>>3: nstrip=c0&31
// (32 strips of 32 cols), mslot=c0>>5 (2). Wave tile 32m x 32n.
__global__ __launch_bounds__(512, 4) void k_gemm2s(
    const ushort_t* __restrict__ hs, const ushort_t* __restrict__ Wsd,
    const ushort_t* __restrict__ contrib, float* __restrict__ out) {
  constexpr int K = 512;
  __shared__ __attribute__((aligned(16))) ushort_t lB[32 * 512];      // 32KB
  __shared__ __attribute__((aligned(16))) ushort_t lA[8][2][32 * 64]; // 32KB

  const int xcd = blockIdx.x & 7;
  const int c0 = blockIdx.x >> 3;
  const int nstrip = c0 & 31;
  const int mslot = c0 >> 5;
  const int nBase = nstrip * 32;
  const int rb = xcd * 1024;                 // token range base

  const int wid = threadIdx.x >> 6, lane = threadIdx.x & 63;
  const int l15 = lane & 15, lq = lane >> 4;

  // stage B: 2048 16B-slots, 512 thr x 4
#pragma unroll
  for (int i = 0; i < 4; ++i) {
    const int L = i * 512 + threadIdx.x;
    const int row = L >> 6, s = L & 63;
    const int ss = s ^ row;
    gload_lds16(Wsd + (size_t)(nBase + row) * K + ss * 8,
                ((char*)lB) + (size_t)(L & ~63) * 16);
  }

  char* lAw = (char*)&lA[wid][0][0];
  auto stageA = [&](int buf, int chunk, int kc) {
#pragma unroll
    for (int i = 0; i < 4; ++i) {
      const int L = i * 64 + lane;
      const int row = L >> 3, s = L & 7;
      const int ss = s ^ (row & 7);
      gload_lds16(hs + (size_t)(rb + chunk * 32 + row) * K + kc * 64 + ss * 8,
                  lAw + (size_t)buf * 4096 + (size_t)i * 1024);
    }
  };

  int cw = mslot * 8 + wid;                  // 0..15, chunks stride 16, 32 total
  stageA(0, cw, 0);
  asm volatile("s_waitcnt vmcnt(4)" ::: "memory");
  __builtin_amdgcn_s_barrier();

  int buf = 0;
  for (int rep = 0; rep < 2; ++rep) {
    f32x4 acc[2][2];
#pragma unroll
    for (int mi = 0; mi < 2; ++mi)
#pragma unroll
      for (int ni = 0; ni < 2; ++ni) acc[mi][ni] = (f32x4){0.f, 0.f, 0.f, 0.f};

    for (int kc = 0; kc < 8; ++kc) {
      int nc = cw, nk = kc + 1;
      if (nk == 8) { nk = 0; nc = cw + 16; }
      if (nc < 32) {
        stageA(buf ^ 1, nc, nk);
        asm volatile("s_waitcnt vmcnt(4)" ::: "memory");
      } else {
        asm volatile("s_waitcnt vmcnt(0)" ::: "memory");
      }
      const char* sA = lAw + buf * 4096;
#pragma unroll
      for (int kk = 0; kk < 2; ++kk) {
        bf16x8 af[2], bfr[2];
#pragma unroll
        for (int mi = 0; mi < 2; ++mi) {
          const int row = mi * 16 + l15;
          af[mi] = *(const bf16x8*)(sA + row * 128 + (((kk * 4 + lq) ^ (row & 7)) << 4));
        }
#pragma unroll
        for (int ni = 0; ni < 2; ++ni) {
          const int brow = ni * 16 + l15;
          const int ck = kc * 8 + kk * 4 + lq;
          bfr[ni] = *(const bf16x8*)((const char*)lB + brow * 1024 +
                                     ((ck ^ brow) << 4));
        }
#pragma unroll
        for (int mi = 0; mi < 2; ++mi)
#pragma unroll
          for (int ni = 0; ni < 2; ++ni)
            acc[mi][ni] = __builtin_amdgcn_mfma_f32_16x16x32_bf16(
                af[mi], bfr[ni], acc[mi][ni], 0, 0, 0);
      }
      buf ^= 1;
    }

#pragma unroll
    for (int mi = 0; mi < 2; ++mi) {
#pragma unroll
      for (int r = 0; r < 4; ++r) {
        const int gg = rb + cw * 32 + mi * 16 + lq * 4 + r;
#pragma unroll
        for (int ni = 0; ni < 2; ++ni) {
          const int c = nBase + ni * 16 + l15;
          out[(size_t)gg * 1024 + c] = acc[mi][ni][r]
              + bf2f(contrib[(size_t)(gg * 2) * 1024 + c])
              + bf2f(contrib[(size_t)(gg * 2 + 1) * 1024 + c]);
        }
      }
    }
    cw += 16;
  }
  asm volatile("s_waitcnt vmcnt(0)" ::: "memory");
}

// ---------------- launch ----------------
extern "C" void kernel_launch(void* const* d_in, const int* in_sizes, int n_in,
                              void* d_out, int out_size, void* d_ws, size_t ws_size,
                              hipStream_t stream) {
  (void)in_sizes; (void)n_in; (void)out_size; (void)ws_size;
  const float* x      = (const float*)d_in[0];
  const float* Wg     = (const float*)d_in[1];
  const float* w_gate = (const float*)d_in[2];
  const float* w_up   = (const float*)d_in[3];
  const float* w_down = (const float*)d_in[4];
  const float* sg     = (const float*)d_in[5];
  const float* su     = (const float*)d_in[6];
  const float* sd     = (const float*)d_in[7];
  float* out = (float*)d_out;

  char* ws = (char*)d_ws;
  size_t o = 0;
  ushort_t* xb    = (ushort_t*)(ws + o); o += (size_t)TOK * DIM * 2;
  ushort_t* Wsh1  = (ushort_t*)(ws + o); o += (size_t)1024 * 1024 * 2;
  ushort_t* Wsd   = (ushort_t*)(ws + o); o += (size_t)1024 * 512 * 2;
  ushort_t* Wgu   = (ushort_t*)(ws + o); o += (size_t)NEXP * 512 * 1024 * 2;
  ushort_t* Wd    = (ushort_t*)(ws + o); o += (size_t)NEXP * 1024 * 256 * 2;
  ushort_t* hs    = (ushort_t*)(ws + o); o += (size_t)TOK * 512 * 2;
  ushort_t* he    = (ushort_t*)(ws + o); o += (size_t)TOK * TOPK * 256 * 2;
  int*   tid   = (int*)(ws + o);   o += (size_t)TOK * TOPK * 4;
  float* tw    = (float*)(ws + o); o += (size_t)TOK * TOPK * 4;
  int*   tok   = (int*)(ws + o);   o += (size_t)TOK * TOPK * 4;
  float* wgt   = (float*)(ws + o); o += (size_t)TOK * TOPK * 4;
  int*   dstrow= (int*)(ws + o);   o += (size_t)TOK * TOPK * 4;
  int*   cnt   = (int*)(ws + o);   o += 64;
  int*   cnt2  = (int*)(ws + o);   o += 64;
  ushort_t* contrib = (ushort_t*)(ws + o);  // [TOK*2][1024] bf16, token-major

  hipMemsetAsync(cnt, 0, 128, stream);

  k_prep<<<1792, 256, 0, stream>>>(x, Wg, xb, tid, tw, cnt, sg, su,
                                   w_gate, w_up, Wsh1, Wgu);
  k_scatter<<<TOK / 256, 256, 0, stream>>>(tid, tw, cnt, cnt2, tok, wgt, dstrow);

  k_gemm1<<<1664, 256, 0, stream>>>(xb, Wgu, Wsh1, he, hs, tok, cnt,
                                    sd, w_down, Wsd, Wd);
  // routed GEMM2: 512 blocks, 2/CU, barrier-free per-wave pipeline
  k_gemm2r<<<512, 512, 0, stream>>>(he, Wd, contrib, wgt, cnt, dstrow);
  // shared GEMM2 + combine: 512 blocks, 2/CU
  k_gemm2s<<<512, 512, 0, stream>>>(hs, Wsd, contrib, out);
}

// Round 22
// 150.051 us; speedup vs baseline: 1.0314x; 1.0314x over previous
//
#include <hip/hip_runtime.h>
#include <stdint.h>

#define TOK   8192
#define DIM   1024
#define NEXP  8
#define TOPK  2
#define WPAD  1028

typedef unsigned short ushort_t;
typedef __attribute__((ext_vector_type(8))) short bf16x8;
typedef __attribute__((ext_vector_type(4))) float f32x4;

__device__ __forceinline__ unsigned short f2bf(float f) {
  unsigned int u = __float_as_uint(f);
  u += 0x7fffu + ((u >> 16) & 1u);
  return (unsigned short)(u >> 16);
}
__device__ __forceinline__ float bf2f(ushort_t u) {
  return __uint_as_float(((unsigned int)u) << 16);
}

__device__ __forceinline__ void gload_lds16(const void* g, void* l) {
  __builtin_amdgcn_global_load_lds(
      (const __attribute__((address_space(1))) void*)(uintptr_t)g,
      (__attribute__((address_space(3))) void*)(unsigned int)(uintptr_t)l,
      16, 0, 0);
}

// ---- prep: router+cast+histogram (0..511) | Wsh1/Wgu transpose (512..1791) --
__global__ __launch_bounds__(256) void k_prep(
    const float* __restrict__ x, const float* __restrict__ Wg,
    ushort_t* __restrict__ xb, int* __restrict__ tid, float* __restrict__ tw,
    int* __restrict__ cnt,
    const float* __restrict__ sg, const float* __restrict__ su,
    const float* __restrict__ wgm, const float* __restrict__ wu,
    ushort_t* __restrict__ Wsh1, ushort_t* __restrict__ Wgu) {
  __shared__ float sm[WPAD * NEXP > 64 * 65 ? WPAD * NEXP : 64 * 65];
  __shared__ int hh[NEXP];
  if (blockIdx.x < 512) {
    if (threadIdx.x < NEXP) hh[threadIdx.x] = 0;
    for (int j = threadIdx.x; j < DIM * NEXP; j += 256)
      sm[(j & 7) * WPAD + (j >> 3)] = Wg[j];
    __syncthreads();
    const int wid = threadIdx.x >> 6, lane = threadIdx.x & 63;
#pragma unroll
    for (int tt2 = 0; tt2 < 4; ++tt2) {
      const int t = blockIdx.x * 16 + wid * 4 + tt2;
      const float* xr = x + (size_t)t * DIM;
      ushort_t* xw = xb + (size_t)t * DIM;
      float acc[NEXP];
#pragma unroll
      for (int e = 0; e < NEXP; ++e) acc[e] = 0.f;
#pragma unroll
      for (int k = 0; k < 4; ++k) {
        const int i = k * 256 + lane * 4;
        const float4 xv = *(const float4*)(xr + i);
        union { ushort_t u[4]; uint2 v; } s;
        s.u[0] = f2bf(xv.x); s.u[1] = f2bf(xv.y);
        s.u[2] = f2bf(xv.z); s.u[3] = f2bf(xv.w);
        *(uint2*)(xw + i) = s.v;
#pragma unroll
        for (int e = 0; e < NEXP; ++e) {
          const float4 wv = *(const float4*)&sm[e * WPAD + i];
          acc[e] += xv.x * wv.x + xv.y * wv.y + xv.z * wv.z + xv.w * wv.w;
        }
      }
#pragma unroll
      for (int e = 0; e < NEXP; ++e) {
        float v = acc[e];
#pragma unroll
        for (int o = 32; o > 0; o >>= 1) v += __shfl_xor(v, o);
        acc[e] = v;
      }
      if (lane == 0) {
        float mx = acc[0];
#pragma unroll
        for (int e = 1; e < NEXP; ++e) mx = fmaxf(mx, acc[e]);
        float p[NEXP]; float s = 0.f;
#pragma unroll
        for (int e = 0; e < NEXP; ++e) { p[e] = __expf(acc[e] - mx); s += p[e]; }
        const float inv = 1.f / s;
#pragma unroll
        for (int e = 0; e < NEXP; ++e) p[e] *= inv;
        int i1 = 0; float s1 = p[0];
#pragma unroll
        for (int e = 1; e < NEXP; ++e) if (p[e] > s1) { s1 = p[e]; i1 = e; }
        int i2 = -1; float s2 = -1.f;
#pragma unroll
        for (int e = 0; e < NEXP; ++e) if (e != i1 && p[e] > s2) { s2 = p[e]; i2 = e; }
        tid[t * 2] = i1; tid[t * 2 + 1] = i2;
        tw[t * 2] = s1;  tw[t * 2 + 1] = s2;
        atomicAdd(&hh[i1], 1);
        atomicAdd(&hh[i2], 1);
      }
    }
    __syncthreads();
    if (threadIdx.x < NEXP) {
      const int v = hh[threadIdx.x];
      if (v) atomicAdd(&cnt[threadIdx.x], v);
    }
    return;
  }
  // ---- transpose (ilv only): one 64x64 tile per block ----
  int b = blockIdx.x - 512;
  const float* src; ushort_t* dst; int R, C, r0, c0, pp;
  if (b < 256) {
    pp = b & 1; const int t = b >> 1;
    src = pp ? su : sg; dst = Wsh1; R = 1024; C = 512;
    c0 = (t & 7) * 64; r0 = (t >> 3) * 64;
  } else {
    b -= 256; pp = b & 1; const int t = b >> 1;
    const int e = t >> 6; const int tt = t & 63;
    src = (pp ? wu : wgm) + (size_t)e * 1024 * 256;
    dst = Wgu + (size_t)e * 512 * 1024; R = 1024; C = 256;
    c0 = (tt & 3) * 64; r0 = (tt >> 2) * 64;
  }
  float (*tt4)[65] = (float(*)[65])sm;
  const int row16 = threadIdx.x >> 4;
  const int q16   = threadIdx.x & 15;
#pragma unroll
  for (int i = 0; i < 64; i += 16) {
    const float4 v = *(const float4*)&src[(size_t)(r0 + row16 + i) * C + c0 + q16 * 4];
    tt4[q16 * 4 + 0][row16 + i] = v.x;
    tt4[q16 * 4 + 1][row16 + i] = v.y;
    tt4[q16 * 4 + 2][row16 + i] = v.z;
    tt4[q16 * 4 + 3][row16 + i] = v.w;
  }
  __syncthreads();
#pragma unroll
  for (int i = 0; i < 64; i += 16) {
    const int n = c0 + row16 + i;
    const int drow = 2 * n + pp;
    const float4 v = *(const float4*)&tt4[row16 + i][q16 * 4];
    union { ushort_t u[4]; uint2 w; } s4;
    s4.u[0] = f2bf(v.x); s4.u[1] = f2bf(v.y);
    s4.u[2] = f2bf(v.z); s4.u[3] = f2bf(v.w);
    *(uint2*)&dst[(size_t)drow * R + r0 + q16 * 4] = s4.w;
  }
}

// ---------------- ballot-ranked scatter (inline off from cnt) ----------------
__global__ __launch_bounds__(256) void k_scatter(const int* __restrict__ tid,
                                                 const float* __restrict__ tw,
                                                 const int* __restrict__ cnt,
                                                 int* __restrict__ cnt2,
                                                 int* __restrict__ tok,
                                                 float* __restrict__ wgt,
                                                 int* __restrict__ dstrow) {
  int offv[NEXP];
  {
    int run = 0;
#pragma unroll
    for (int e = 0; e < NEXP; ++e) { offv[e] = run; run += cnt[e]; }
  }
  const int t = blockIdx.x * 256 + threadIdx.x;
  const int lane = threadIdx.x & 63;
#pragma unroll
  for (int j = 0; j < TOPK; ++j) {
    const int e = tid[t * 2 + j];
    const float w = tw[t * 2 + j];
    int slot = 0;
#pragma unroll
    for (int ee = 0; ee < NEXP; ++ee) {
      const unsigned long long m = __ballot(e == ee);
      if (m) {
        const int r = __popcll(m & ((1ull << lane) - 1ull));
        const int leader = __ffsll((unsigned long long)m) - 1;
        int base = 0;
        if (lane == leader) base = atomicAdd(&cnt2[ee], (int)__popcll(m));
        base = __shfl(base, leader);
        if (e == ee) slot = offv[ee] + base + r;
      }
    }
    tok[slot] = t;
    wgt[slot] = w;
    dstrow[slot] = t * 2 + j;
  }
}

// ---- GEMM1 (merged routed+shared, r13 structure) + Wsd/Wd transpose tail ----
__global__ __launch_bounds__(256) void k_gemm1(
    const ushort_t* __restrict__ A0, const ushort_t* __restrict__ Bgu,
    const ushort_t* __restrict__ Bsh,
    ushort_t* __restrict__ he, ushort_t* __restrict__ hs,
    const int* __restrict__ tok, const int* __restrict__ cnt,
    const float* __restrict__ sd, const float* __restrict__ wdn,
    ushort_t* __restrict__ Wsd, ushort_t* __restrict__ Wd) {
  constexpr int K = 1024, NB = 4, NGROUP = 16, MBSLOT = 16;
  constexpr int NWG = NGROUP * MBSLOT * NB;
  __shared__ __attribute__((aligned(16))) ushort_t lA[2][128 * 64];
  __shared__ __attribute__((aligned(16))) ushort_t lB[2][128 * 64];

  if (blockIdx.x >= 1024) {
    int b = blockIdx.x - 1024;
    const float* src; ushort_t* dst; int R, C, r0, c0;
    if (b < 128) {
      src = sd; dst = Wsd; R = 512; C = 1024;
      c0 = (b & 15) * 64; r0 = (b >> 4) * 64;
    } else {
      b -= 128; const int e = b >> 6; const int tt = b & 63;
      src = wdn + (size_t)e * 256 * 1024;
      dst = Wd + (size_t)e * 1024 * 256; R = 256; C = 1024;
      c0 = (tt & 15) * 64; r0 = (tt >> 4) * 64;
    }
    float (*tt4)[65] = (float(*)[65])lA;
    const int row16 = threadIdx.x >> 4;
    const int q16   = threadIdx.x & 15;
#pragma unroll
    for (int i = 0; i < 64; i += 16) {
      const float4 v = *(const float4*)&src[(size_t)(r0 + row16 + i) * C + c0 + q16 * 4];
      tt4[q16 * 4 + 0][row16 + i] = v.x;
      tt4[q16 * 4 + 1][row16 + i] = v.y;
      tt4[q16 * 4 + 2][row16 + i] = v.z;
      tt4[q16 * 4 + 3][row16 + i] = v.w;
    }
    __syncthreads();
#pragma unroll
    for (int i = 0; i < 64; i += 16) {
      const int n = c0 + row16 + i;
      const float4 v = *(const float4*)&tt4[row16 + i][q16 * 4];
      union { ushort_t u[4]; uint2 w; } s4;
      s4.u[0] = f2bf(v.x); s4.u[1] = f2bf(v.y);
      s4.u[2] = f2bf(v.z); s4.u[3] = f2bf(v.w);
      *(uint2*)&dst[(size_t)n * R + r0 + q16 * 4] = s4.w;
    }
    return;
  }

  const int wg = (blockIdx.x % 8) * (NWG / 8) + blockIdx.x / 8;
  const int g = wg / (MBSLOT * NB);
  const int rem = wg % (MBSLOT * NB);
  const int mbslot = rem / NB;
  const int nb = rem % NB;
  const int nBase = nb * 128;

  int m_e, offE = 0, rowq = 0, hh = 0;
  bool gat = false;
  const ushort_t* Abase = A0;
  const ushort_t* Bblk;
  if (g < 8) {
    gat = true; m_e = cnt[g];
    for (int e = 0; e < NEXP; ++e) offE += (e < g) ? cnt[e] : 0;
    Bblk = Bgu + (size_t)g * 512 * 1024;
  } else {
    const int q = (g - 8) >> 1; hh = (g - 8) & 1;
    rowq = q * 2048; m_e = 2048;
    Abase = A0 + (size_t)rowq * 1024;
    Bblk = Bsh + (size_t)hh * 512 * 1024;
  }
  if (m_e == 0) return;

  const int wid = threadIdx.x >> 6, lane = threadIdx.x & 63;
  const int wm = wid >> 1, wn = wid & 1;
  const int l15 = lane & 15, lq = lane >> 4;

  const ushort_t* bptr[4];
#pragma unroll
  for (int cc = 0; cc < 4; ++cc) {
    const int c = wid * 4 + cc;
    const int rl = c * 8 + (lane >> 3);
    const int slot = (lane & 7) ^ (rl & 7);
    bptr[cc] = Bblk + (size_t)(nBase + rl) * K + slot * 8;
  }

  for (int mb = mbslot; mb * 128 < m_e; mb += MBSLOT) {
    const int mBase = mb * 128;
    const ushort_t* aptr[4];
#pragma unroll
    for (int cc = 0; cc < 4; ++cc) {
      const int c = wid * 4 + cc;
      const int rl = c * 8 + (lane >> 3);
      const int slot = (lane & 7) ^ (rl & 7);
      const int gr = mBase + rl;
      const int gc = (gr < m_e) ? gr : (m_e - 1);
      const ushort_t* ar;
      if (gat) ar = A0 + (size_t)tok[offE + gc] * 1024;
      else     ar = Abase + (size_t)gc * K;
      aptr[cc] = ar + slot * 8;
    }

    auto stage = [&](int buf, int ktv) {
#pragma unroll
      for (int cc = 0; cc < 4; ++cc) {
        const int c = wid * 4 + cc;
        gload_lds16(aptr[cc] + ktv, &lA[buf][c * 512]);
        gload_lds16(bptr[cc] + ktv, &lB[buf][c * 512]);
      }
    };

    f32x4 acc[4][4];
#pragma unroll
    for (int mi = 0; mi < 4; ++mi)
#pragma unroll
      for (int ni = 0; ni < 4; ++ni) acc[mi][ni] = (f32x4){0.f, 0.f, 0.f, 0.f};

    stage(0, 0);
    int cur = 0;
    for (int kt = 0; kt < K; kt += 64) {
      if (kt + 64 < K) {
        stage(cur ^ 1, kt + 64);
        asm volatile("s_waitcnt vmcnt(8)" ::: "memory");
      } else {
        asm volatile("s_waitcnt vmcnt(0)" ::: "memory");
      }
      __builtin_amdgcn_s_barrier();
#pragma unroll
      for (int kk = 0; kk < 2; ++kk) {
        bf16x8 af[4], bfr[4];
#pragma unroll
        for (int mi = 0; mi < 4; ++mi) {
          const int row = wm * 64 + mi * 16 + l15;
          const int cb = ((kk * 32 + lq * 8) * 2) ^ ((row & 7) << 4);
          af[mi] = *(const bf16x8*)((const char*)lA + cur * 16384 + row * 128 + cb);
        }
#pragma unroll
        for (int ni = 0; ni < 4; ++ni) {
          const int row = wn * 64 + ni * 16 + l15;
          const int cb = ((kk * 32 + lq * 8) * 2) ^ ((row & 7) << 4);
          bfr[ni] = *(const bf16x8*)((const char*)lB + cur * 16384 + row * 128 + cb);
        }
#pragma unroll
        for (int mi = 0; mi < 4; ++mi)
#pragma unroll
          for (int ni = 0; ni < 4; ++ni)
            acc[mi][ni] = __builtin_amdgcn_mfma_f32_16x16x32_bf16(
                af[mi], bfr[ni], acc[mi][ni], 0, 0, 0);
      }
      __builtin_amdgcn_s_barrier();
      cur ^= 1;
    }

#pragma unroll
    for (int mi = 0; mi < 4; ++mi) {
#pragma unroll
      for (int r = 0; r < 4; ++r) {
        const int gg = mBase + wm * 64 + mi * 16 + lq * 4 + r;
        const bool ok = gg < m_e;
#pragma unroll
        for (int ni = 0; ni < 4; ++ni) {
          const float v = acc[mi][ni][r];
          const int c = nBase + wn * 64 + ni * 16 + l15;
          const float o = __shfl_xor(v, 1);
          if (!(c & 1) && ok) {
            const float hv = (v / (1.f + __expf(-v))) * o;
            if (gat) he[(size_t)(offE + gg) * 256 + (c >> 1)] = f2bf(hv);
            else     hs[(size_t)(rowq + gg) * 512 + hh * 256 + (c >> 1)] = f2bf(hv);
          }
        }
      }
    }
  }
}

// ---- GEMM2r: routed. B-resident + per-wave private A pipeline, NO barriers --
__global__ __launch_bounds__(512, 1) void k_gemm2r(
    const ushort_t* __restrict__ he, const ushort_t* __restrict__ Wd,
    ushort_t* __restrict__ contrib, const float* __restrict__ wgt,
    const int* __restrict__ cnt, const int* __restrict__ dstrow) {
  constexpr int K = 256;
  __shared__ __attribute__((aligned(16))) ushort_t lB[128 * 256];     // 64KB
  __shared__ __attribute__((aligned(16))) ushort_t lA[8][2][32 * 64]; // 64KB

  const int e = blockIdx.x & 7;
  const int c0 = blockIdx.x >> 3;
  const int nb = c0 & 7;
  const int mslot = c0 >> 3;
  const int nBase = nb * 128;

  const int m_e = cnt[e];
  int offE = 0;
  for (int ee = 0; ee < NEXP; ++ee) offE += (ee < e) ? cnt[ee] : 0;
  const ushort_t* Abase = he + (size_t)offE * K;
  const ushort_t* Bblk = Wd + (size_t)e * 1024 * K;

  const int wid = threadIdx.x >> 6, lane = threadIdx.x & 63;
  const int l15 = lane & 15, lq = lane >> 4;

  if (m_e > 0) {
#pragma unroll
    for (int i = 0; i < 8; ++i) {
      const int L = (wid * 8 + i) * 64 + lane;
      const int row = L >> 5, s = L & 31;
      const int ss = s ^ (row & 31);
      gload_lds16(Bblk + (size_t)(nBase + row) * K + ss * 8,
                  ((char*)lB) + (size_t)(wid * 8 + i) * 1024);
    }
  }

  char* lAw = (char*)&lA[wid][0][0];
  auto stageA = [&](int buf, int chunk, int kc) {
#pragma unroll
    for (int i = 0; i < 4; ++i) {
      const int L = i * 64 + lane;
      const int row = L >> 3, s = L & 7;
      const int ss = s ^ (row & 7);
      int gr = chunk * 32 + row;
      if (gr >= m_e) gr = m_e - 1;
      gload_lds16(Abase + (size_t)gr * K + kc * 64 + ss * 8,
                  lAw + (size_t)buf * 4096 + (size_t)i * 1024);
    }
  };

  int cw = mslot * 8 + wid;
  bool active = (m_e > 0) && (cw * 32 < m_e);
  if (m_e > 0) stageA(0, active ? cw : 0, 0);
  asm volatile("s_waitcnt vmcnt(4)" ::: "memory");
  __builtin_amdgcn_s_barrier();
  if (!active) return;

  int buf = 0;
  while (active) {
    f32x4 acc[2][8];
#pragma unroll
    for (int mi = 0; mi < 2; ++mi)
#pragma unroll
      for (int ni = 0; ni < 8; ++ni) acc[mi][ni] = (f32x4){0.f, 0.f, 0.f, 0.f};

    for (int kc = 0; kc < 4; ++kc) {
      int nc = cw, nk = kc + 1;
      if (nk == 4) { nk = 0; nc = cw + 32; }
      if (nc * 32 < m_e) {
        stageA(buf ^ 1, nc, nk);
        asm volatile("s_waitcnt vmcnt(4)" ::: "memory");
      } else {
        asm volatile("s_waitcnt vmcnt(0)" ::: "memory");
      }
      const char* sA = lAw + buf * 4096;
#pragma unroll
      for (int kk = 0; kk < 2; ++kk) {
        bf16x8 af[2], bfr[8];
#pragma unroll
        for (int mi = 0; mi < 2; ++mi) {
          const int row = mi * 16 + l15;
          af[mi] = *(const bf16x8*)(sA + row * 128 + (((kk * 4 + lq) ^ (row & 7)) << 4));
        }
#pragma unroll
        for (int ni = 0; ni < 8; ++ni) {
          const int brow = ni * 16 + l15;
          const int ck = kc * 8 + kk * 4 + lq;
          bfr[ni] = *(const bf16x8*)((const char*)lB + brow * 512 +
                                     ((ck ^ (brow & 31)) << 4));
        }
#pragma unroll
        for (int mi = 0; mi < 2; ++mi)
#pragma unroll
          for (int ni = 0; ni < 8; ++ni)
            acc[mi][ni] = __builtin_amdgcn_mfma_f32_16x16x32_bf16(
                af[mi], bfr[ni], acc[mi][ni], 0, 0, 0);
      }
      buf ^= 1;
    }

#pragma unroll
    for (int mi = 0; mi < 2; ++mi) {
#pragma unroll
      for (int r = 0; r < 4; ++r) {
        const int gg = cw * 32 + mi * 16 + lq * 4 + r;
        if (gg < m_e) {
          const float w = wgt[offE + gg];
          const int dr = dstrow[offE + gg];
#pragma unroll
          for (int ni = 0; ni < 8; ++ni) {
            const int c = nBase + ni * 16 + l15;
            contrib[(size_t)dr * 1024 + c] = f2bf(acc[mi][ni][r] * w);
          }
        }
      }
    }
    cw += 32;
    active = cw * 32 < m_e;
  }
  asm volatile("s_waitcnt vmcnt(0)" ::: "memory");
}

// ---- GEMM2s: shared + combine. B-resident + per-wave A pipeline, no barriers
__global__ __launch_bounds__(512, 1) void k_gemm2s(
    const ushort_t* __restrict__ hs, const ushort_t* __restrict__ Wsd,
    const ushort_t* __restrict__ contrib, float* __restrict__ out) {
  constexpr int K = 512;
  __shared__ __attribute__((aligned(16))) ushort_t lB[64 * 512];      // 64KB
  __shared__ __attribute__((aligned(16))) ushort_t lA[8][2][32 * 64]; // 64KB

  const int wg = (blockIdx.x & 7) * 32 + (blockIdx.x >> 3);
  const int nstrip = wg >> 4;
  const int mslot = wg & 15;
  const int nBase = nstrip * 64;

  const int wid = threadIdx.x >> 6, lane = threadIdx.x & 63;
  const int l15 = lane & 15, lq = lane >> 4;

#pragma unroll
  for (int i = 0; i < 8; ++i) {
    const int L = (wid * 8 + i) * 64 + lane;
    const int row = L >> 6, s = L & 63;
    const int ss = s ^ row;
    gload_lds16(Wsd + (size_t)(nBase + row) * K + ss * 8,
                ((char*)lB) + (size_t)(wid * 8 + i) * 1024);
  }

  char* lAw = (char*)&lA[wid][0][0];
  auto stageA = [&](int buf, int chunk, int kc) {
#pragma unroll
    for (int i = 0; i < 4; ++i) {
      const int L = i * 64 + lane;
      const int row = L >> 3, s = L & 7;
      const int ss = s ^ (row & 7);
      gload_lds16(hs + (size_t)(chunk * 32 + row) * K + kc * 64 + ss * 8,
                  lAw + (size_t)buf * 4096 + (size_t)i * 1024);
    }
  };

  int cw = mslot * 8 + wid;
  stageA(0, cw, 0);
  asm volatile("s_waitcnt vmcnt(4)" ::: "memory");
  __builtin_amdgcn_s_barrier();

  int buf = 0;
  for (int rep = 0; rep < 2; ++rep) {
    f32x4 acc[2][4];
#pragma unroll
    for (int mi = 0; mi < 2; ++mi)
#pragma unroll
      for (int ni = 0; ni < 4; ++ni) acc[mi][ni] = (f32x4){0.f, 0.f, 0.f, 0.f};

    for (int kc = 0; kc < 8; ++kc) {
      int nc = cw, nk = kc + 1;
      if (nk == 8) { nk = 0; nc = cw + 128; }
      if (nc < 256) {
        stageA(buf ^ 1, nc, nk);
        asm volatile("s_waitcnt vmcnt(4)" ::: "memory");
      } else {
        asm volatile("s_waitcnt vmcnt(0)" ::: "memory");
      }
      const char* sA = lAw + buf * 4096;
#pragma unroll
      for (int kk = 0; kk < 2; ++kk) {
        bf16x8 af[2], bfr[4];
#pragma unroll
        for (int mi = 0; mi < 2; ++mi) {
          const int row = mi * 16 + l15;
          af[mi] = *(const bf16x8*)(sA + row * 128 + (((kk * 4 + lq) ^ (row & 7)) << 4));
        }
#pragma unroll
        for (int ni = 0; ni < 4; ++ni) {
          const int brow = ni * 16 + l15;
          const int ck = kc * 8 + kk * 4 + lq;
          bfr[ni] = *(const bf16x8*)((const char*)lB + brow * 1024 +
                                     ((ck ^ brow) << 4));
        }
#pragma unroll
        for (int mi = 0; mi < 2; ++mi)
#pragma unroll
          for (int ni = 0; ni < 4; ++ni)
            acc[mi][ni] = __builtin_amdgcn_mfma_f32_16x16x32_bf16(
                af[mi], bfr[ni], acc[mi][ni], 0, 0, 0);
      }
      buf ^= 1;
    }

#pragma unroll
    for (int mi = 0; mi < 2; ++mi) {
#pragma unroll
      for (int r = 0; r < 4; ++r) {
        const int gg = cw * 32 + mi * 16 + lq * 4 + r;
#pragma unroll
        for (int ni = 0; ni < 4; ++ni) {
          const int c = nBase + ni * 16 + l15;
          out[(size_t)gg * 1024 + c] = acc[mi][ni][r]
              + bf2f(contrib[(size_t)(gg * 2) * 1024 + c])
              + bf2f(contrib[(size_t)(gg * 2 + 1) * 1024 + c]);
        }
      }
    }
    cw += 128;
  }
  asm volatile("s_waitcnt vmcnt(0)" ::: "memory");
}

// ---------------- launch ----------------
extern "C" void kernel_launch(void* const* d_in, const int* in_sizes, int n_in,
                              void* d_out, int out_size, void* d_ws, size_t ws_size,
                              hipStream_t stream) {
  (void)in_sizes; (void)n_in; (void)out_size; (void)ws_size;
  const float* x      = (const float*)d_in[0];
  const float* Wg     = (const float*)d_in[1];
  const float* w_gate = (const float*)d_in[2];
  const float* w_up   = (const float*)d_in[3];
  const float* w_down = (const float*)d_in[4];
  const float* sg     = (const float*)d_in[5];
  const float* su     = (const float*)d_in[6];
  const float* sd     = (const float*)d_in[7];
  float* out = (float*)d_out;

  char* ws = (char*)d_ws;
  size_t o = 0;
  ushort_t* xb    = (ushort_t*)(ws + o); o += (size_t)TOK * DIM * 2;
  ushort_t* Wsh1  = (ushort_t*)(ws + o); o += (size_t)1024 * 1024 * 2;
  ushort_t* Wsd   = (ushort_t*)(ws + o); o += (size_t)1024 * 512 * 2;
  ushort_t* Wgu   = (ushort_t*)(ws + o); o += (size_t)NEXP * 512 * 1024 * 2;
  ushort_t* Wd    = (ushort_t*)(ws + o); o += (size_t)NEXP * 1024 * 256 * 2;
  ushort_t* hs    = (ushort_t*)(ws + o); o += (size_t)TOK * 512 * 2;
  ushort_t* he    = (ushort_t*)(ws + o); o += (size_t)TOK * TOPK * 256 * 2;
  int*   tid   = (int*)(ws + o);   o += (size_t)TOK * TOPK * 4;
  float* tw    = (float*)(ws + o); o += (size_t)TOK * TOPK * 4;
  int*   tok   = (int*)(ws + o);   o += (size_t)TOK * TOPK * 4;
  float* wgt   = (float*)(ws + o); o += (size_t)TOK * TOPK * 4;
  int*   dstrow= (int*)(ws + o);   o += (size_t)TOK * TOPK * 4;
  int*   cnt   = (int*)(ws + o);   o += 64;   // cnt[8] then cnt2[8] adjacent
  int*   cnt2  = (int*)(ws + o);   o += 64;
  ushort_t* contrib = (ushort_t*)(ws + o);  // [TOK*2][1024] bf16, token-major

  // zero cnt + cnt2 (128 B) — async, graph-capture-safe
  hipMemsetAsync(cnt, 0, 128, stream);

  // prep: router+cast+histogram + Wsh1/Wgu transpose
  k_prep<<<1792, 256, 0, stream>>>(x, Wg, xb, tid, tw, cnt, sg, su,
                                   w_gate, w_up, Wsh1, Wgu);
  k_scatter<<<TOK / 256, 256, 0, stream>>>(tid, tw, cnt, cnt2, tok, wgt, dstrow);

  // GEMM1 (1024 gemm blocks + 640 Wsd/Wd transpose blocks)
  k_gemm1<<<1664, 256, 0, stream>>>(xb, Wgu, Wsh1, he, hs, tok, cnt,
                                    sd, w_down, Wsd, Wd);
  // routed GEMM2 -> token-major bf16 contrib (barrier-free wave pipeline)
  k_gemm2r<<<256, 512, 0, stream>>>(he, Wd, contrib, wgt, cnt, dstrow);
  // shared GEMM2 + combine -> out (barrier-free wave pipeline)
  k_gemm2s<<<256, 512, 0, stream>>>(hs, Wsd, contrib, out);
}